// Round 13
// baseline (428.600 us; speedup 1.0000x reference)
//
#include <hip/hip_runtime.h>

// EncoderBlock: x:[2,2048,1024] FP32 in/out. Internal fp16 MFMA.
// B=2 S=2048 D=1024 H=16 DH=64 FF=4096, T=4096 tokens.
// ws (32MB): R0 8MB: h -> woT -> h(LN2)
//            R1..R3 24MB: fused QKV [4096][3072] (V slice unused) -> attn-out in Q slice
//                         -> f(R1+R2) + wscratch(R3 only after wo-gemm)
// d_out (16MB): wqkvT fp16 [0,6MB) + Vt fp16 [6MB,14MB) -> x1 fp32 -> final output.
// GEMM map (hard-won ledger):
//   QKV  -> gemm_t128 + Vt-transposed epilogue (768 blk = 3/CU)  [r5,r8]
//   FFN1 -> gemm_t 64x128 (1024 blk = 4/CU; 128^2 LOST twice)    [r2,r6]
//   wo/FFN2 -> gemm_t32 32x128 (1024 blk = 4/CU; was 512=2/CU — occupancy>reuse,
//              same lesson as FFN1; 2-phase db LOST r7)          [r13]
// attn ledger: QBLK=64 2-buffer 32KB, FROZEN at proven 85.7us core (r6/r8).
//   LOST: QBLK=128 (r9), bit_cast pb (r7), 3-buf vmcnt ring (r10), setprio (r11).
//   WON:  Q-in-KVs-buf staging (r6), max3 tree + defer-max (r5,r6),
//         wo-convt rides in attn launch z=0 (r12).
// launches 13->10 (r12): pre_kernel (ln1+qkv convt), post_kernel (ln2+ffn0 convt).

typedef _Float16 half8 __attribute__((ext_vector_type(8)));
typedef _Float16 half4 __attribute__((ext_vector_type(4)));
typedef __fp16 fp16x2 __attribute__((ext_vector_type(2)));
typedef float floatx4 __attribute__((ext_vector_type(4)));

#define MAX3(a, b, c) fmaxf(fmaxf((a), (b)), (c))

__device__ __forceinline__ void async16(const void* g, void* l) {
    __builtin_amdgcn_global_load_lds((const __attribute__((address_space(1))) unsigned int*)g,
                                     (__attribute__((address_space(3))) unsigned int*)l,
                                     16, 0, 0);
}

// ---------------- LayerNorm body fp32 -> fp16 (ddof=1, g*(x-mean)/(std+eps)+b) ----
__device__ __forceinline__ void ln_body(const float* __restrict__ x,
                                        const float* __restrict__ g,
                                        const float* __restrict__ be,
                                        _Float16* __restrict__ out, int row) {
    int tid = threadIdx.x;
    floatx4 v = ((const floatx4*)(x + (size_t)row * 1024))[tid];
    float s = 0.f, ss = 0.f;
#pragma unroll
    for (int i = 0; i < 4; i++) { s += v[i]; ss += v[i] * v[i]; }
#pragma unroll
    for (int off = 1; off < 64; off <<= 1) {
        s += __shfl_xor(s, off);
        ss += __shfl_xor(ss, off);
    }
    __shared__ float sm[8];
    int wave = tid >> 6, lane = tid & 63;
    if (lane == 0) { sm[wave] = s; sm[wave + 4] = ss; }
    __syncthreads();
    s = sm[0] + sm[1] + sm[2] + sm[3];
    ss = sm[4] + sm[5] + sm[6] + sm[7];
    float mean = s * (1.f / 1024.f);
    float var = (ss - s * mean) * (1.f / 1023.f);
    float rs = 1.f / (sqrtf(fmaxf(var, 0.f)) + 1e-6f);
    floatx4 gv = ((const floatx4*)g)[tid];
    floatx4 bv = ((const floatx4*)be)[tid];
    half4 o;
#pragma unroll
    for (int i = 0; i < 4; i++) o[i] = (_Float16)(gv[i] * (v[i] - mean) * rs + bv[i]);
    ((half4*)(out + (size_t)row * 1024))[tid] = o;
}

// ------- Transpose-convert core: W[Kr][Nr] fp32 (row stride ldW) -> WT[Nr][Kr] fp16 * scale --
__device__ __forceinline__ void convt_core(float (*t)[65], const float* __restrict__ W, int ldW,
                                           _Float16* __restrict__ WT, int Kr, float scale,
                                           int n0, int k0) {
    int tid = threadIdx.x;
    int r = tid >> 4, c4 = (tid & 15) * 4;
#pragma unroll
    for (int p = 0; p < 4; p++) {
        floatx4 v = *(const floatx4*)(W + (size_t)(k0 + r + p * 16) * ldW + n0 + c4);
#pragma unroll
        for (int j = 0; j < 4; j++) t[c4 + j][r + p * 16] = v[j];
    }
    __syncthreads();
#pragma unroll
    for (int p = 0; p < 4; p++) {
        int rr = r + p * 16;
        half4 o;
#pragma unroll
        for (int j = 0; j < 4; j++) o[j] = (_Float16)(t[rr][c4 + j] * scale);
        *(half4*)(WT + (size_t)(n0 + rr) * Kr + k0 + c4) = o;
    }
}

__device__ __forceinline__ void convt_body(const float* __restrict__ W, int ldW,
                                           _Float16* __restrict__ WT, int Kr, float scale,
                                           int n0, int k0) {
    __shared__ float t[64][65];
    convt_core(t, W, ldW, WT, Kr, scale, n0, k0);
}

// ---- pre_kernel: ln1 (blocks 0..4095) + wq/wk/wv convt (blocks 4096..4863) ----
__global__ __launch_bounds__(256) void pre_kernel(const float* __restrict__ x,
                                                  const float* __restrict__ g1,
                                                  const float* __restrict__ be1,
                                                  _Float16* __restrict__ h,
                                                  const float* __restrict__ wq,
                                                  const float* __restrict__ wk,
                                                  const float* __restrict__ wv,
                                                  _Float16* __restrict__ QT) {
    int bid = blockIdx.x;
    if (bid < 4096) { ln_body(x, g1, be1, h, bid); return; }
    int rem = bid - 4096;
    int z = rem >> 8, xy = rem & 255;
    const float* W = (z == 0) ? wq : (z == 1) ? wk : wv;
    convt_body(W, 1024, QT + (size_t)z * 1024 * 1024, 1024, (z == 0) ? 0.125f : 1.f,
               (xy & 15) * 64, (xy >> 4) * 64);
}

// ---- post_kernel: ln2 (blocks 0..4095) + FFN half-0 convts (blocks 4096..6143) ----
__global__ __launch_bounds__(256) void post_kernel(const float* __restrict__ x1,
                                                   const float* __restrict__ g2,
                                                   const float* __restrict__ be2,
                                                   _Float16* __restrict__ h,
                                                   const float* __restrict__ w1h,
                                                   _Float16* __restrict__ w1T,
                                                   const float* __restrict__ w2h,
                                                   _Float16* __restrict__ w2T) {
    int bid = blockIdx.x;
    if (bid < 4096) { ln_body(x1, g2, be2, h, bid); return; }
    int rem = bid - 4096;            // 0..2047
    int z = rem >> 10, xy = rem & 1023;
    int xx = xy & 31, yy = xy >> 5;
    if (z == 0) {
        if (yy < 16) convt_body(w1h, 4096, w1T, 1024, 1.f, xx * 64, yy * 64);   // 32x16
    } else {
        if (xx < 16) convt_body(w2h, 1024, w2T, 2048, 1.f, xx * 64, yy * 64);   // 16x32
    }
}

// two convt jobs in one launch (z selects); blocks outside the job's grid exit. (FFN half-1)
__global__ __launch_bounds__(256) void convt_pair_kernel(const float* __restrict__ Wa, int ldWa,
                                                         _Float16* __restrict__ WTa, int Kra,
                                                         int gxa, int gya,
                                                         const float* __restrict__ Wb, int ldWb,
                                                         _Float16* __restrict__ WTb, int Krb,
                                                         int gxb, int gyb) {
    int z = blockIdx.z;
    const float* W = z ? Wb : Wa;
    _Float16* WT = z ? WTb : WTa;
    int ldW = z ? ldWb : ldWa;
    int Kr = z ? Krb : Kra;
    int gx = z ? gxb : gxa, gy = z ? gyb : gya;
    if ((int)blockIdx.x >= gx || (int)blockIdx.y >= gy) return;
    convt_body(W, ldW, WT, Kr, 1.f, blockIdx.x * 64, blockIdx.y * 64);
}

// ------- MFMA GEMM 64x128: C = [relu](A@BT^T + bias) + res --------
// A [M][lda] fp16, BT [N][K] fp16. 4 waves x (32x64), BK=64. FFN1 (1024 blk = 4/CU).
__global__ __launch_bounds__(256) void gemm_t(const _Float16* __restrict__ A, int lda,
                                              const _Float16* __restrict__ BT,
                                              const float* __restrict__ bias,
                                              const float* res, void* Cout,
                                              int N, int K, int relu_flag, int out_fp16) {
    __shared__ _Float16 As[64 * 64];    // 8KB
    __shared__ _Float16 Bs[128 * 64];   // 16KB
    int tid = threadIdx.x;
    int wave = tid >> 6, lane = tid & 63, quad = lane >> 4, l15 = lane & 15;
    int bm = blockIdx.y * 64, bn = blockIdx.x * 128;
    int wr = (wave & 1) * 32, wc = (wave >> 1) * 64;
    int lrow = lane >> 3, lch = lane & 7;

    floatx4 acc[2][4];
#pragma unroll
    for (int im = 0; im < 2; im++)
#pragma unroll
        for (int in = 0; in < 4; in++)
#pragma unroll
            for (int r = 0; r < 4; r++) acc[im][in][r] = 0.f;

    for (int k0 = 0; k0 < K; k0 += 64) {
        __syncthreads();
#pragma unroll
        for (int ia = 0; ia < 2; ia++) {
            int g = 2 * wave + ia;
            int row = g * 8 + lrow;
            int ch = lch ^ (row & 7);
            async16(A + (size_t)(bm + row) * lda + k0 + ch * 8, &As[g * 512]);
        }
#pragma unroll
        for (int ib = 0; ib < 4; ib++) {
            int g = 4 * wave + ib;
            int row = g * 8 + lrow;
            int ch = lch ^ (row & 7);
            async16(BT + (size_t)(bn + row) * K + k0 + ch * 8, &Bs[g * 512]);
        }
        __syncthreads();

        half8 af[2][2], bf[4][2];
#pragma unroll
        for (int kk = 0; kk < 2; kk++) {
#pragma unroll
            for (int im = 0; im < 2; im++) {
                int m = wr + im * 16 + l15;
                af[im][kk] = *(const half8*)&As[m * 64 + ((((kk << 2) | quad) ^ (m & 7)) << 3)];
            }
#pragma unroll
            for (int in = 0; in < 4; in++) {
                int n = wc + in * 16 + l15;
                bf[in][kk] = *(const half8*)&Bs[n * 64 + ((((kk << 2) | quad) ^ (n & 7)) << 3)];
            }
        }
#pragma unroll
        for (int kk = 0; kk < 2; kk++)
#pragma unroll
            for (int im = 0; im < 2; im++)
#pragma unroll
                for (int in = 0; in < 4; in++)
                    acc[im][in] = __builtin_amdgcn_mfma_f32_16x16x32_f16(af[im][kk], bf[in][kk],
                                                                         acc[im][in], 0, 0, 0);
    }
#pragma unroll
    for (int im = 0; im < 2; im++)
#pragma unroll
        for (int in = 0; in < 4; in++)
#pragma unroll
            for (int r = 0; r < 4; r++) {
                int row = bm + wr + im * 16 + quad * 4 + r;
                int col = bn + wc + in * 16 + l15;
                float val = acc[im][in][r];
                if (bias) val += bias[col];
                if (relu_flag) val = fmaxf(val, 0.f);
                if (res) val += res[(size_t)row * N + col];
                if (out_fp16) ((_Float16*)Cout)[(size_t)row * N + col] = (_Float16)val;
                else          ((float*)Cout)[(size_t)row * N + col] = val;
            }
}

// ------- MFMA GEMM 32x128: same structure, half M-tile -> 2x grid = 4 blocks/CU ----
// For wo/FFN2 (N=1024: grid (8,128)=1024 blk). 20KB LDS. 4 waves x (16x64), acc 1x4.
__global__ __launch_bounds__(256) void gemm_t32(const _Float16* __restrict__ A, int lda,
                                                const _Float16* __restrict__ BT,
                                                const float* __restrict__ bias,
                                                const float* res, void* Cout,
                                                int N, int K, int relu_flag, int out_fp16) {
    __shared__ _Float16 As[32 * 64];    // 4KB
    __shared__ _Float16 Bs[128 * 64];   // 16KB
    int tid = threadIdx.x;
    int wave = tid >> 6, lane = tid & 63, quad = lane >> 4, l15 = lane & 15;
    int bm = blockIdx.y * 32, bn = blockIdx.x * 128;
    int wr = (wave & 1) * 16, wc = (wave >> 1) * 64;
    int lrow = lane >> 3, lch = lane & 7;

    floatx4 acc[4];
#pragma unroll
    for (int in = 0; in < 4; in++)
#pragma unroll
        for (int r = 0; r < 4; r++) acc[in][r] = 0.f;

    for (int k0 = 0; k0 < K; k0 += 64) {
        __syncthreads();
        {   // A tile: 32x64 = one async16 per thread (group = wave, 8 rows each)
            int row = wave * 8 + lrow;
            int ch = lch ^ (row & 7);
            async16(A + (size_t)(bm + row) * lda + k0 + ch * 8, &As[wave * 512]);
        }
#pragma unroll
        for (int ib = 0; ib < 4; ib++) {
            int g = 4 * wave + ib;
            int row = g * 8 + lrow;
            int ch = lch ^ (row & 7);
            async16(BT + (size_t)(bn + row) * K + k0 + ch * 8, &Bs[g * 512]);
        }
        __syncthreads();

        half8 af[2], bf[4][2];
#pragma unroll
        for (int kk = 0; kk < 2; kk++) {
            int m = wr + l15;
            af[kk] = *(const half8*)&As[m * 64 + ((((kk << 2) | quad) ^ (m & 7)) << 3)];
#pragma unroll
            for (int in = 0; in < 4; in++) {
                int n = wc + in * 16 + l15;
                bf[in][kk] = *(const half8*)&Bs[n * 64 + ((((kk << 2) | quad) ^ (n & 7)) << 3)];
            }
        }
#pragma unroll
        for (int kk = 0; kk < 2; kk++)
#pragma unroll
            for (int in = 0; in < 4; in++)
                acc[in] = __builtin_amdgcn_mfma_f32_16x16x32_f16(af[kk], bf[in][kk],
                                                                 acc[in], 0, 0, 0);
    }
#pragma unroll
    for (int in = 0; in < 4; in++)
#pragma unroll
        for (int r = 0; r < 4; r++) {
            int row = bm + wr + quad * 4 + r;
            int col = bn + wc + in * 16 + l15;
            float val = acc[in][r];
            if (bias) val += bias[col];
            if (relu_flag) val = fmaxf(val, 0.f);
            if (res) val += res[(size_t)row * N + col];
            if (out_fp16) ((_Float16*)Cout)[(size_t)row * N + col] = (_Float16)val;
            else          ((float*)Cout)[(size_t)row * N + col] = val;
        }
}

// ------- MFMA GEMM 128x128 (m97 structure): 4 waves x (64x64, 4x4 acc), BK=64, 32KB LDS.
// 2:1 ds_read:MFMA reuse. QKV only (768 blk = 3/CU). Blocks with bn>=2048 (V slice)
// write their output TRANSPOSED into Vt[bh=32][dh=64][s=2048] (kills transv kernel).
__global__ __launch_bounds__(256) void gemm_t128(const _Float16* __restrict__ A, int lda,
                                                 const _Float16* __restrict__ BT,
                                                 _Float16* __restrict__ Cout,
                                                 _Float16* __restrict__ VtOut,
                                                 int N, int K) {
    __shared__ _Float16 As[128 * 64];   // 16KB
    __shared__ _Float16 Bs[128 * 64];   // 16KB
    int tid = threadIdx.x;
    int wave = tid >> 6, lane = tid & 63, quad = lane >> 4, l15 = lane & 15;
    int bm = blockIdx.y * 128, bn = blockIdx.x * 128;
    int wr = (wave & 1) * 64, wc = (wave >> 1) * 64;
    int lrow = lane >> 3, lch = lane & 7;

    floatx4 acc[4][4];
#pragma unroll
    for (int im = 0; im < 4; im++)
#pragma unroll
        for (int in = 0; in < 4; in++)
#pragma unroll
            for (int r = 0; r < 4; r++) acc[im][in][r] = 0.f;

    for (int k0 = 0; k0 < K; k0 += 64) {
        __syncthreads();
#pragma unroll
        for (int ia = 0; ia < 4; ia++) {
            int g = 4 * wave + ia;
            int row = g * 8 + lrow;
            int ch = lch ^ (row & 7);
            async16(A + (size_t)(bm + row) * lda + k0 + ch * 8, &As[g * 512]);
        }
#pragma unroll
        for (int ib = 0; ib < 4; ib++) {
            int g = 4 * wave + ib;
            int row = g * 8 + lrow;
            int ch = lch ^ (row & 7);
            async16(BT + (size_t)(bn + row) * K + k0 + ch * 8, &Bs[g * 512]);
        }
        __syncthreads();

        half8 af[4][2], bf[4][2];
#pragma unroll
        for (int kk = 0; kk < 2; kk++) {
#pragma unroll
            for (int im = 0; im < 4; im++) {
                int m = wr + im * 16 + l15;
                af[im][kk] = *(const half8*)&As[m * 64 + ((((kk << 2) | quad) ^ (m & 7)) << 3)];
            }
#pragma unroll
            for (int in = 0; in < 4; in++) {
                int n = wc + in * 16 + l15;
                bf[in][kk] = *(const half8*)&Bs[n * 64 + ((((kk << 2) | quad) ^ (n & 7)) << 3)];
            }
        }
#pragma unroll
        for (int kk = 0; kk < 2; kk++)
#pragma unroll
            for (int im = 0; im < 4; im++)
#pragma unroll
                for (int in = 0; in < 4; in++)
                    acc[im][in] = __builtin_amdgcn_mfma_f32_16x16x32_f16(af[im][kk], bf[in][kk],
                                                                         acc[im][in], 0, 0, 0);
    }
    if (VtOut && bn >= 2048) {
#pragma unroll
        for (int im = 0; im < 4; im++) {
            int rowbase = bm + wr + im * 16 + quad * 4;
            int b = rowbase >> 11, s = rowbase & 2047;
#pragma unroll
            for (int in = 0; in < 4; in++) {
                int vcol = bn - 2048 + wc + in * 16 + l15;
                int bh = b * 16 + (vcol >> 6);
                int dh = vcol & 63;
                half4 o;
#pragma unroll
                for (int r = 0; r < 4; r++) o[r] = (_Float16)acc[im][in][r];
                *(half4*)&VtOut[((size_t)bh * 64 + dh) * 2048 + s] = o;
            }
        }
    } else {
#pragma unroll
        for (int im = 0; im < 4; im++)
#pragma unroll
            for (int in = 0; in < 4; in++)
#pragma unroll
                for (int r = 0; r < 4; r++) {
                    int row = bm + wr + im * 16 + quad * 4 + r;
                    int col = bn + wc + in * 16 + l15;
                    Cout[(size_t)row * N + col] = (_Float16)acc[im][in][r];
                }
    }
}

// ---------------- Flash attention v3 (r6/r8 proven config, FROZEN) --------------
// S^T trick + double-buffered K/V. Q pre-scaled via wq. One barrier per kt.
// Q staged into KVs[1][0] (dead after bq hoist) -> 32KB LDS.
// z=0 blocks instead run the wo transpose-convert (aliasing this kernel's LDS).
template <int BUF>
__device__ __forceinline__ void attn_step(const half8* const (&kfp)[2][4][2],
                                          const half4* const (&vfp)[2][4][4],
                                          const half8 (&bq)[2],
                                          floatx4 (&o_acc)[4],
                                          float& m_i, float& l_i) {
    const float LOG2E = 1.44269504f;
    floatx4 s_acc[4];
#pragma unroll
    for (int jn = 0; jn < 4; jn++)
#pragma unroll
        for (int r = 0; r < 4; r++) s_acc[jn][r] = 0.f;
#pragma unroll
    for (int jn = 0; jn < 4; jn++)
#pragma unroll
        for (int kk = 0; kk < 2; kk++)
            s_acc[jn] = __builtin_amdgcn_mfma_f32_16x16x32_f16(*kfp[BUF][jn][kk], bq[kk],
                                                               s_acc[jn], 0, 0, 0);

    // online softmax with deferred max (THR=8); max3 tree
    float t0 = MAX3(s_acc[0][0], s_acc[0][1], s_acc[0][2]);
    float t1 = MAX3(s_acc[0][3], s_acc[1][0], s_acc[1][1]);
    float t2 = MAX3(s_acc[1][2], s_acc[1][3], s_acc[2][0]);
    float t3 = MAX3(s_acc[2][1], s_acc[2][2], s_acc[2][3]);
    float t4 = MAX3(s_acc[3][0], s_acc[3][1], s_acc[3][2]);
    float mx = MAX3(MAX3(t0, t1, t2), fmaxf(t3, t4), s_acc[3][3]);
    mx = fmaxf(mx, __shfl_xor(mx, 16));
    mx = fmaxf(mx, __shfl_xor(mx, 32));
    if (!__all(mx <= m_i + 8.f)) {
        float mnew = fmaxf(m_i, mx);
        float dd = m_i - mnew;
        float alpha = (dd < -60.f) ? 0.f : __expf(dd);
        l_i *= alpha;
#pragma unroll
        for (int im = 0; im < 4; im++)
#pragma unroll
            for (int r = 0; r < 4; r++) o_acc[im][r] *= alpha;
        m_i = mnew;
    }
    float m2 = m_i * LOG2E;

    float sj[4];
    half4 pb[4];   // P^T C-layout regs ARE B-fragments of mfma_16x16x16 (k=quad*4+j)
#pragma unroll
    for (int jn = 0; jn < 4; jn++) {
        float p0 = exp2f(fmaf(s_acc[jn][0], LOG2E, -m2));
        float p1 = exp2f(fmaf(s_acc[jn][1], LOG2E, -m2));
        float p2 = exp2f(fmaf(s_acc[jn][2], LOG2E, -m2));
        float p3 = exp2f(fmaf(s_acc[jn][3], LOG2E, -m2));
        sj[jn] = (p0 + p1) + (p2 + p3);
        fp16x2 lo = __builtin_amdgcn_cvt_pkrtz(p0, p1);
        fp16x2 hi = __builtin_amdgcn_cvt_pkrtz(p2, p3);
        pb[jn][0] = (_Float16)lo[0]; pb[jn][1] = (_Float16)lo[1];
        pb[jn][2] = (_Float16)hi[0]; pb[jn][3] = (_Float16)hi[1];
    }
    float sum = (sj[0] + sj[1]) + (sj[2] + sj[3]);
    sum += __shfl_xor(sum, 16);
    sum += __shfl_xor(sum, 32);
    l_i += sum;

#pragma unroll
    for (int im = 0; im < 4; im++)
#pragma unroll
        for (int ks = 0; ks < 4; ks++)
            o_acc[im] = __builtin_amdgcn_mfma_f32_16x16x16f16(*vfp[BUF][im][ks], pb[ks],
                                                              o_acc[im], 0, 0, 0);
}

__global__ __launch_bounds__(256) void attn_kernel(const _Float16* Q,
                                                   const _Float16* __restrict__ K,
                                                   const _Float16* __restrict__ Vt,
                                                   _Float16* O, int ld,
                                                   const float* __restrict__ woW,
                                                   _Float16* __restrict__ woT) {
    __shared__ _Float16 KVs[2][2][64 * 64];   // [buf][0=K,1=V] 32KB; Q pre-staged in KVs[1][0]
    if (blockIdx.z == 0) {
        // wo transpose-convert rides along (256 of 1024 z=0 blocks); aliases KVs as scratch.
        if (blockIdx.x < 16 && blockIdx.y < 16)
            convt_core((float(*)[65])&KVs[0][0][0], woW, 1024, woT, 1024, 1.f,
                       blockIdx.x * 64, blockIdx.y * 64);
        return;
    }
    int qt = blockIdx.x, bh = blockIdx.y;
    int b = bh >> 4, h = bh & 15;
    int col0 = h * 64, tbase = b * 2048;
    int tid = threadIdx.x;
    int wave = tid >> 6, lane = tid & 63, quad = lane >> 4, l15 = lane & 15;
    int lrow = lane >> 3, lch = lane & 7;

    const _Float16* kg[2];
    const _Float16* vg[2];
    const size_t kadv = (size_t)64 * ld;
#pragma unroll
    for (int i = 0; i < 2; i++) {
        int g = 2 * wave + i;
        int row = g * 8 + lrow;
        int ch = lch ^ (row & 7);
        kg[i] = K + (size_t)(tbase + row) * ld + col0 + ch * 8;
        vg[i] = Vt + ((size_t)bh * 64 + row) * 2048 + ch * 8;
        async16(Q + (size_t)(tbase + qt * 64 + row) * ld + col0 + ch * 8, &KVs[1][0][g * 512]);
        async16(kg[i], &KVs[0][0][g * 512]);
        async16(vg[i], &KVs[0][1][g * 512]);
        kg[i] += kadv;
        vg[i] += 64;
    }
    __syncthreads();   // drains Q + buf0

    // hoist Q fragments from KVs[1][0]; wave-local rows, lgkm wait before loop prefetch lands.
    int rowq = 16 * wave + l15;
    half8 bq[2];
#pragma unroll
    for (int kk = 0; kk < 2; kk++)
        bq[kk] = *(const half8*)&KVs[1][0][rowq * 64 + ((((kk << 2) | quad) ^ (rowq & 7)) << 3)];
    asm volatile("s_waitcnt lgkmcnt(0)" ::: "memory");
    __builtin_amdgcn_sched_barrier(0);

    const half8* kfp[2][4][2];
    const half4* vfp[2][4][4];
#pragma unroll
    for (int bb = 0; bb < 2; bb++) {
#pragma unroll
        for (int jn = 0; jn < 4; jn++) {
            int rowk = 16 * jn + l15;
#pragma unroll
            for (int kk = 0; kk < 2; kk++)
                kfp[bb][jn][kk] = (const half8*)
                    &KVs[bb][0][rowk * 64 + ((((kk << 2) | quad) ^ (rowk & 7)) << 3)];
        }
#pragma unroll
        for (int im = 0; im < 4; im++) {
            int rowv = 16 * im + l15;
#pragma unroll
            for (int ks = 0; ks < 4; ks++) {
                int off = rowv * 128 + ((((2 * ks) | (quad >> 1)) ^ (rowv & 7)) << 4)
                          + (quad & 1) * 8;
                vfp[bb][im][ks] = (const half4*)((const char*)KVs[bb][1] + off);
            }
        }
    }

    floatx4 o_acc[4];
#pragma unroll
    for (int im = 0; im < 4; im++)
#pragma unroll
        for (int r = 0; r < 4; r++) o_acc[im][r] = 0.f;
    float m_i = -1e30f, l_i = 0.f;

#pragma unroll 1
    for (int kt2 = 0; kt2 < 16; kt2++) {
        if (kt2) __syncthreads();
#pragma unroll
        for (int i = 0; i < 2; i++) {
            async16(kg[i], &KVs[1][0][(2 * wave + i) * 512]);
            async16(vg[i], &KVs[1][1][(2 * wave + i) * 512]);
            kg[i] += kadv;
            vg[i] += 64;
        }
        attn_step<0>(kfp, vfp, bq, o_acc, m_i, l_i);

        __syncthreads();
        if (kt2 < 15) {
#pragma unroll
            for (int i = 0; i < 2; i++) {
                async16(kg[i], &KVs[0][0][(2 * wave + i) * 512]);
                async16(vg[i], &KVs[0][1][(2 * wave + i) * 512]);
                kg[i] += kadv;
                vg[i] += 64;
            }
        }
        attn_step<1>(kfp, vfp, bq, o_acc, m_i, l_i);
    }

    float rl = 1.f / l_i;
#pragma unroll
    for (int im = 0; im < 4; im++) {
        half4 o;
#pragma unroll
        for (int r = 0; r < 4; r++) o[r] = (_Float16)(o_acc[im][r] * rl);
        *(half4*)&O[(size_t)(tbase + qt * 64 + wave * 16 + l15) * ld + col0 + im * 16 + quad * 4] = o;
    }
}

extern "C" void kernel_launch(void* const* d_in, const int* in_sizes, int n_in,
                              void* d_out, int out_size, void* d_ws, size_t ws_size,
                              hipStream_t stream) {
    const float* x   = (const float*)d_in[0];
    const float* wq  = (const float*)d_in[1];
    const float* wk  = (const float*)d_in[2];
    const float* wv  = (const float*)d_in[3];
    const float* wo  = (const float*)d_in[4];
    const float* w1  = (const float*)d_in[5];
    const float* b1  = (const float*)d_in[6];
    const float* w2  = (const float*)d_in[7];
    const float* b2  = (const float*)d_in[8];
    const float* g1  = (const float*)d_in[9];
    const float* be1 = (const float*)d_in[10];
    const float* g2  = (const float*)d_in[11];
    const float* be2 = (const float*)d_in[12];

    const size_t M1 = (size_t)1 << 20;
    _Float16* R0  = (_Float16*)d_ws;       // h -> woT -> h(LN2)
    _Float16* QKV = R0 + 4 * M1;           // [4096][3072] spans R0+4M1..R0+16M1 (V slice unused)
    _Float16* R3  = R0 + 12 * M1;          // valid scratch only after wo-gemm

    _Float16* wqkvT = (_Float16*)d_out;    // [3072][1024] fp16, bytes [0,6MB)
    _Float16* VtD = wqkvT + 3 * M1;        // Vt [32][64][2048] fp16, bytes [6MB,14MB)
    float* x1 = (float*)d_out;
    float* out = (float*)d_out;

    dim3 blk(256);

    // ln1 + wq/wk/wv convt fused (1/sqrt(64) folded into wq)
    pre_kernel<<<4864, blk, 0, stream>>>(x, g1, be1, R0, wq, wk, wv, wqkvT);
    // fused QKV GEMM (128x128, 768 blk = 3/CU): Q,K -> QKV slices; V -> VtD transposed
    gemm_t128<<<dim3(24, 32), blk, 0, stream>>>(R0, 1024, wqkvT, QKV, VtD, 3072, 1024);
    // attention (z=1) + wo convt into R0 (z=0; R0 dead during attn)
    _Float16* woT = R0;
    attn_kernel<<<dim3(32, 32, 2), blk, 0, stream>>>(QKV, QKV + 1024, VtD, QKV, 3072, wo, woT);
    // x1 = attnout @ wo + x -> d_out  (32x128 tile, 1024 blk = 4/CU)
    gemm_t32<<<dim3(8, 128), blk, 0, stream>>>(QKV, 3072, woT, nullptr, x, x1, 1024, 1024, 0, 0);
    // ln2 + FFN half-0 convts fused (R3 scratch valid: wo-gemm done)
    _Float16* w1Th = R3;
    _Float16* w2Th = R3 + 2 * M1;
    post_kernel<<<6144, blk, 0, stream>>>(x1, g2, be2, R0, w1, w1Th, w2, w2Th);
    // FFN half 0
    _Float16* f = QKV;
    gemm_t<<<dim3(16, 64), blk, 0, stream>>>(R0, 1024, w1Th, b1, nullptr, f, 2048, 1024, 1, 1);
    gemm_t32<<<dim3(8, 128), blk, 0, stream>>>(f, 2048, w2Th, nullptr, x1, out, 1024, 2048, 0, 0);
    // FFN half 1
    convt_pair_kernel<<<dim3(32, 32, 2), blk, 0, stream>>>(
        w1 + 2048, 4096, w1Th, 1024, 32, 16,
        w2 + (size_t)2048 * 1024, 1024, w2Th, 2048, 16, 32);
    gemm_t<<<dim3(16, 64), blk, 0, stream>>>(R0, 1024, w1Th, b1 + 2048, nullptr, f, 2048, 1024, 1, 1);
    gemm_t32<<<dim3(8, 128), blk, 0, stream>>>(f, 2048, w2Th, b2, x1, out, 1024, 2048, 0, 0);
}

// Round 14
// 415.680 us; speedup vs baseline: 1.0311x; 1.0311x over previous
//
#include <hip/hip_runtime.h>

// EncoderBlock: x:[2,2048,1024] FP32 in/out. Internal fp16 MFMA.
// B=2 S=2048 D=1024 H=16 DH=64 FF=4096, T=4096 tokens.
// ws (32MB): R0 8MB: h -> woT -> h(LN2)
//            R1..R3 24MB: fused QKV [4096][3072] (V slice unused) -> attn-out in Q slice
//                         -> f(R1+R2) + wscratch(R3 only after wo-gemm)
// d_out (16MB): wqkvT fp16 [0,6MB) + Vt fp16 [6MB,14MB) -> x1 fp32 -> final output.
// GEMM map (hard-won ledger):
//   QKV  -> gemm_t128 + Vt epilogue + XCD swizzle (768 blk = 3/CU)  [r5,r8,r14]
//   FFN1 -> gemm_t 64x128 (1024 blk = 4/CU; 128^2 LOST twice r2,r6)
//   wo/FFN2 -> gemm_t 64x128 (2-phase db LOST r7; 32x128 LOST r13 +14us:
//              shrinking tile doubles B-staging per unit output)
// attn ledger: QBLK=64 2-buffer 32KB, FROZEN (85.7us core, r6/r8).
//   LOST: QBLK=128 (r9), bit_cast pb (r7), 3-buf vmcnt ring (r10), setprio (r11).
//   WON:  Q-in-KVs-buf staging (r6), max3 + defer-max (r5,r6), wo-convt rides z=0 (r12).
// launches 13->10 (r12): pre_kernel (ln1+qkv convt), post_kernel (ln2+ffn0 convt).

typedef _Float16 half8 __attribute__((ext_vector_type(8)));
typedef _Float16 half4 __attribute__((ext_vector_type(4)));
typedef __fp16 fp16x2 __attribute__((ext_vector_type(2)));
typedef float floatx4 __attribute__((ext_vector_type(4)));

#define MAX3(a, b, c) fmaxf(fmaxf((a), (b)), (c))

__device__ __forceinline__ void async16(const void* g, void* l) {
    __builtin_amdgcn_global_load_lds((const __attribute__((address_space(1))) unsigned int*)g,
                                     (__attribute__((address_space(3))) unsigned int*)l,
                                     16, 0, 0);
}

// ---------------- LayerNorm body fp32 -> fp16 (ddof=1, g*(x-mean)/(std+eps)+b) ----
__device__ __forceinline__ void ln_body(const float* __restrict__ x,
                                        const float* __restrict__ g,
                                        const float* __restrict__ be,
                                        _Float16* __restrict__ out, int row) {
    int tid = threadIdx.x;
    floatx4 v = ((const floatx4*)(x + (size_t)row * 1024))[tid];
    float s = 0.f, ss = 0.f;
#pragma unroll
    for (int i = 0; i < 4; i++) { s += v[i]; ss += v[i] * v[i]; }
#pragma unroll
    for (int off = 1; off < 64; off <<= 1) {
        s += __shfl_xor(s, off);
        ss += __shfl_xor(ss, off);
    }
    __shared__ float sm[8];
    int wave = tid >> 6, lane = tid & 63;
    if (lane == 0) { sm[wave] = s; sm[wave + 4] = ss; }
    __syncthreads();
    s = sm[0] + sm[1] + sm[2] + sm[3];
    ss = sm[4] + sm[5] + sm[6] + sm[7];
    float mean = s * (1.f / 1024.f);
    float var = (ss - s * mean) * (1.f / 1023.f);
    float rs = 1.f / (sqrtf(fmaxf(var, 0.f)) + 1e-6f);
    floatx4 gv = ((const floatx4*)g)[tid];
    floatx4 bv = ((const floatx4*)be)[tid];
    half4 o;
#pragma unroll
    for (int i = 0; i < 4; i++) o[i] = (_Float16)(gv[i] * (v[i] - mean) * rs + bv[i]);
    ((half4*)(out + (size_t)row * 1024))[tid] = o;
}

// ------- Transpose-convert core: W[Kr][Nr] fp32 (row stride ldW) -> WT[Nr][Kr] fp16 * scale --
__device__ __forceinline__ void convt_core(float (*t)[65], const float* __restrict__ W, int ldW,
                                           _Float16* __restrict__ WT, int Kr, float scale,
                                           int n0, int k0) {
    int tid = threadIdx.x;
    int r = tid >> 4, c4 = (tid & 15) * 4;
#pragma unroll
    for (int p = 0; p < 4; p++) {
        floatx4 v = *(const floatx4*)(W + (size_t)(k0 + r + p * 16) * ldW + n0 + c4);
#pragma unroll
        for (int j = 0; j < 4; j++) t[c4 + j][r + p * 16] = v[j];
    }
    __syncthreads();
#pragma unroll
    for (int p = 0; p < 4; p++) {
        int rr = r + p * 16;
        half4 o;
#pragma unroll
        for (int j = 0; j < 4; j++) o[j] = (_Float16)(t[rr][c4 + j] * scale);
        *(half4*)(WT + (size_t)(n0 + rr) * Kr + k0 + c4) = o;
    }
}

__device__ __forceinline__ void convt_body(const float* __restrict__ W, int ldW,
                                           _Float16* __restrict__ WT, int Kr, float scale,
                                           int n0, int k0) {
    __shared__ float t[64][65];
    convt_core(t, W, ldW, WT, Kr, scale, n0, k0);
}

// ---- pre_kernel: ln1 (blocks 0..4095) + wq/wk/wv convt (blocks 4096..4863) ----
__global__ __launch_bounds__(256) void pre_kernel(const float* __restrict__ x,
                                                  const float* __restrict__ g1,
                                                  const float* __restrict__ be1,
                                                  _Float16* __restrict__ h,
                                                  const float* __restrict__ wq,
                                                  const float* __restrict__ wk,
                                                  const float* __restrict__ wv,
                                                  _Float16* __restrict__ QT) {
    int bid = blockIdx.x;
    if (bid < 4096) { ln_body(x, g1, be1, h, bid); return; }
    int rem = bid - 4096;
    int z = rem >> 8, xy = rem & 255;
    const float* W = (z == 0) ? wq : (z == 1) ? wk : wv;
    convt_body(W, 1024, QT + (size_t)z * 1024 * 1024, 1024, (z == 0) ? 0.125f : 1.f,
               (xy & 15) * 64, (xy >> 4) * 64);
}

// ---- post_kernel: ln2 (blocks 0..4095) + FFN half-0 convts (blocks 4096..6143) ----
__global__ __launch_bounds__(256) void post_kernel(const float* __restrict__ x1,
                                                   const float* __restrict__ g2,
                                                   const float* __restrict__ be2,
                                                   _Float16* __restrict__ h,
                                                   const float* __restrict__ w1h,
                                                   _Float16* __restrict__ w1T,
                                                   const float* __restrict__ w2h,
                                                   _Float16* __restrict__ w2T) {
    int bid = blockIdx.x;
    if (bid < 4096) { ln_body(x1, g2, be2, h, bid); return; }
    int rem = bid - 4096;            // 0..2047
    int z = rem >> 10, xy = rem & 1023;
    int xx = xy & 31, yy = xy >> 5;
    if (z == 0) {
        if (yy < 16) convt_body(w1h, 4096, w1T, 1024, 1.f, xx * 64, yy * 64);   // 32x16
    } else {
        if (xx < 16) convt_body(w2h, 1024, w2T, 2048, 1.f, xx * 64, yy * 64);   // 16x32
    }
}

// two convt jobs in one launch (z selects); blocks outside the job's grid exit. (FFN half-1)
__global__ __launch_bounds__(256) void convt_pair_kernel(const float* __restrict__ Wa, int ldWa,
                                                         _Float16* __restrict__ WTa, int Kra,
                                                         int gxa, int gya,
                                                         const float* __restrict__ Wb, int ldWb,
                                                         _Float16* __restrict__ WTb, int Krb,
                                                         int gxb, int gyb) {
    int z = blockIdx.z;
    const float* W = z ? Wb : Wa;
    _Float16* WT = z ? WTb : WTa;
    int ldW = z ? ldWb : ldWa;
    int Kr = z ? Krb : Kra;
    int gx = z ? gxb : gxa, gy = z ? gyb : gya;
    if ((int)blockIdx.x >= gx || (int)blockIdx.y >= gy) return;
    convt_body(W, ldW, WT, Kr, 1.f, blockIdx.x * 64, blockIdx.y * 64);
}

// ------- MFMA GEMM 64x128: C = [relu](A@BT^T + bias) + res --------
// A [M][lda] fp16, BT [N][K] fp16. 4 waves x (32x64), BK=64. FFN1/wo/FFN2.
__global__ __launch_bounds__(256) void gemm_t(const _Float16* __restrict__ A, int lda,
                                              const _Float16* __restrict__ BT,
                                              const float* __restrict__ bias,
                                              const float* res, void* Cout,
                                              int N, int K, int relu_flag, int out_fp16) {
    __shared__ _Float16 As[64 * 64];    // 8KB
    __shared__ _Float16 Bs[128 * 64];   // 16KB
    int tid = threadIdx.x;
    int wave = tid >> 6, lane = tid & 63, quad = lane >> 4, l15 = lane & 15;
    int bm = blockIdx.y * 64, bn = blockIdx.x * 128;
    int wr = (wave & 1) * 32, wc = (wave >> 1) * 64;
    int lrow = lane >> 3, lch = lane & 7;

    floatx4 acc[2][4];
#pragma unroll
    for (int im = 0; im < 2; im++)
#pragma unroll
        for (int in = 0; in < 4; in++)
#pragma unroll
            for (int r = 0; r < 4; r++) acc[im][in][r] = 0.f;

    for (int k0 = 0; k0 < K; k0 += 64) {
        __syncthreads();
#pragma unroll
        for (int ia = 0; ia < 2; ia++) {
            int g = 2 * wave + ia;
            int row = g * 8 + lrow;
            int ch = lch ^ (row & 7);
            async16(A + (size_t)(bm + row) * lda + k0 + ch * 8, &As[g * 512]);
        }
#pragma unroll
        for (int ib = 0; ib < 4; ib++) {
            int g = 4 * wave + ib;
            int row = g * 8 + lrow;
            int ch = lch ^ (row & 7);
            async16(BT + (size_t)(bn + row) * K + k0 + ch * 8, &Bs[g * 512]);
        }
        __syncthreads();

        half8 af[2][2], bf[4][2];
#pragma unroll
        for (int kk = 0; kk < 2; kk++) {
#pragma unroll
            for (int im = 0; im < 2; im++) {
                int m = wr + im * 16 + l15;
                af[im][kk] = *(const half8*)&As[m * 64 + ((((kk << 2) | quad) ^ (m & 7)) << 3)];
            }
#pragma unroll
            for (int in = 0; in < 4; in++) {
                int n = wc + in * 16 + l15;
                bf[in][kk] = *(const half8*)&Bs[n * 64 + ((((kk << 2) | quad) ^ (n & 7)) << 3)];
            }
        }
#pragma unroll
        for (int kk = 0; kk < 2; kk++)
#pragma unroll
            for (int im = 0; im < 2; im++)
#pragma unroll
                for (int in = 0; in < 4; in++)
                    acc[im][in] = __builtin_amdgcn_mfma_f32_16x16x32_f16(af[im][kk], bf[in][kk],
                                                                         acc[im][in], 0, 0, 0);
    }
#pragma unroll
    for (int im = 0; im < 2; im++)
#pragma unroll
        for (int in = 0; in < 4; in++)
#pragma unroll
            for (int r = 0; r < 4; r++) {
                int row = bm + wr + im * 16 + quad * 4 + r;
                int col = bn + wc + in * 16 + l15;
                float val = acc[im][in][r];
                if (bias) val += bias[col];
                if (relu_flag) val = fmaxf(val, 0.f);
                if (res) val += res[(size_t)row * N + col];
                if (out_fp16) ((_Float16*)Cout)[(size_t)row * N + col] = (_Float16)val;
                else          ((float*)Cout)[(size_t)row * N + col] = val;
            }
}

// ------- MFMA GEMM 128x128 (m97 structure): 4 waves x (64x64, 4x4 acc), BK=64, 32KB LDS.
// QKV only (grid FIXED 24x32 = 768 blk = 3/CU). T1 XCD swizzle: each XCD owns 3
// consecutive bn-columns x all bm -> its 3 B-panels (768KB) are L2-resident and
// fetched by exactly one XCD. Bijective (768 = 8*96). Blocks with bn>=2048 (V slice)
// write output TRANSPOSED into Vt[bh=32][dh=64][s=2048] (kills transv kernel).
__global__ __launch_bounds__(256) void gemm_t128(const _Float16* __restrict__ A, int lda,
                                                 const _Float16* __restrict__ BT,
                                                 _Float16* __restrict__ Cout,
                                                 _Float16* __restrict__ VtOut,
                                                 int N, int K) {
    __shared__ _Float16 As[128 * 64];   // 16KB
    __shared__ _Float16 Bs[128 * 64];   // 16KB
    int tid = threadIdx.x;
    int wave = tid >> 6, lane = tid & 63, quad = lane >> 4, l15 = lane & 15;
    // XCD swizzle (dispatch order: x fastest; XCD = lin % 8)
    int lin = blockIdx.y * 24 + blockIdx.x;
    int swz = (lin & 7) * 96 + (lin >> 3);
    int bxx = swz / 32;        // 0..23; each XCD covers 3 consecutive bxx
    int byy = swz - bxx * 32;  // 0..31
    int bm = byy * 128, bn = bxx * 128;
    int wr = (wave & 1) * 64, wc = (wave >> 1) * 64;
    int lrow = lane >> 3, lch = lane & 7;

    floatx4 acc[4][4];
#pragma unroll
    for (int im = 0; im < 4; im++)
#pragma unroll
        for (int in = 0; in < 4; in++)
#pragma unroll
            for (int r = 0; r < 4; r++) acc[im][in][r] = 0.f;

    for (int k0 = 0; k0 < K; k0 += 64) {
        __syncthreads();
#pragma unroll
        for (int ia = 0; ia < 4; ia++) {
            int g = 4 * wave + ia;
            int row = g * 8 + lrow;
            int ch = lch ^ (row & 7);
            async16(A + (size_t)(bm + row) * lda + k0 + ch * 8, &As[g * 512]);
        }
#pragma unroll
        for (int ib = 0; ib < 4; ib++) {
            int g = 4 * wave + ib;
            int row = g * 8 + lrow;
            int ch = lch ^ (row & 7);
            async16(BT + (size_t)(bn + row) * K + k0 + ch * 8, &Bs[g * 512]);
        }
        __syncthreads();

        half8 af[4][2], bf[4][2];
#pragma unroll
        for (int kk = 0; kk < 2; kk++) {
#pragma unroll
            for (int im = 0; im < 4; im++) {
                int m = wr + im * 16 + l15;
                af[im][kk] = *(const half8*)&As[m * 64 + ((((kk << 2) | quad) ^ (m & 7)) << 3)];
            }
#pragma unroll
            for (int in = 0; in < 4; in++) {
                int n = wc + in * 16 + l15;
                bf[in][kk] = *(const half8*)&Bs[n * 64 + ((((kk << 2) | quad) ^ (n & 7)) << 3)];
            }
        }
#pragma unroll
        for (int kk = 0; kk < 2; kk++)
#pragma unroll
            for (int im = 0; im < 4; im++)
#pragma unroll
                for (int in = 0; in < 4; in++)
                    acc[im][in] = __builtin_amdgcn_mfma_f32_16x16x32_f16(af[im][kk], bf[in][kk],
                                                                         acc[im][in], 0, 0, 0);
    }
    if (VtOut && bn >= 2048) {
#pragma unroll
        for (int im = 0; im < 4; im++) {
            int rowbase = bm + wr + im * 16 + quad * 4;
            int b = rowbase >> 11, s = rowbase & 2047;
#pragma unroll
            for (int in = 0; in < 4; in++) {
                int vcol = bn - 2048 + wc + in * 16 + l15;
                int bh = b * 16 + (vcol >> 6);
                int dh = vcol & 63;
                half4 o;
#pragma unroll
                for (int r = 0; r < 4; r++) o[r] = (_Float16)acc[im][in][r];
                *(half4*)&VtOut[((size_t)bh * 64 + dh) * 2048 + s] = o;
            }
        }
    } else {
#pragma unroll
        for (int im = 0; im < 4; im++)
#pragma unroll
            for (int in = 0; in < 4; in++)
#pragma unroll
                for (int r = 0; r < 4; r++) {
                    int row = bm + wr + im * 16 + quad * 4 + r;
                    int col = bn + wc + in * 16 + l15;
                    Cout[(size_t)row * N + col] = (_Float16)acc[im][in][r];
                }
    }
}

// ---------------- Flash attention v3 (r6/r8 proven config, FROZEN) --------------
// S^T trick + double-buffered K/V. Q pre-scaled via wq. One barrier per kt.
// Q staged into KVs[1][0] (dead after bq hoist) -> 32KB LDS.
// z=0 blocks instead run the wo transpose-convert (aliasing this kernel's LDS).
template <int BUF>
__device__ __forceinline__ void attn_step(const half8* const (&kfp)[2][4][2],
                                          const half4* const (&vfp)[2][4][4],
                                          const half8 (&bq)[2],
                                          floatx4 (&o_acc)[4],
                                          float& m_i, float& l_i) {
    const float LOG2E = 1.44269504f;
    floatx4 s_acc[4];
#pragma unroll
    for (int jn = 0; jn < 4; jn++)
#pragma unroll
        for (int r = 0; r < 4; r++) s_acc[jn][r] = 0.f;
#pragma unroll
    for (int jn = 0; jn < 4; jn++)
#pragma unroll
        for (int kk = 0; kk < 2; kk++)
            s_acc[jn] = __builtin_amdgcn_mfma_f32_16x16x32_f16(*kfp[BUF][jn][kk], bq[kk],
                                                               s_acc[jn], 0, 0, 0);

    // online softmax with deferred max (THR=8); max3 tree
    float t0 = MAX3(s_acc[0][0], s_acc[0][1], s_acc[0][2]);
    float t1 = MAX3(s_acc[0][3], s_acc[1][0], s_acc[1][1]);
    float t2 = MAX3(s_acc[1][2], s_acc[1][3], s_acc[2][0]);
    float t3 = MAX3(s_acc[2][1], s_acc[2][2], s_acc[2][3]);
    float t4 = MAX3(s_acc[3][0], s_acc[3][1], s_acc[3][2]);
    float mx = MAX3(MAX3(t0, t1, t2), fmaxf(t3, t4), s_acc[3][3]);
    mx = fmaxf(mx, __shfl_xor(mx, 16));
    mx = fmaxf(mx, __shfl_xor(mx, 32));
    if (!__all(mx <= m_i + 8.f)) {
        float mnew = fmaxf(m_i, mx);
        float dd = m_i - mnew;
        float alpha = (dd < -60.f) ? 0.f : __expf(dd);
        l_i *= alpha;
#pragma unroll
        for (int im = 0; im < 4; im++)
#pragma unroll
            for (int r = 0; r < 4; r++) o_acc[im][r] *= alpha;
        m_i = mnew;
    }
    float m2 = m_i * LOG2E;

    float sj[4];
    half4 pb[4];   // P^T C-layout regs ARE B-fragments of mfma_16x16x16 (k=quad*4+j)
#pragma unroll
    for (int jn = 0; jn < 4; jn++) {
        float p0 = exp2f(fmaf(s_acc[jn][0], LOG2E, -m2));
        float p1 = exp2f(fmaf(s_acc[jn][1], LOG2E, -m2));
        float p2 = exp2f(fmaf(s_acc[jn][2], LOG2E, -m2));
        float p3 = exp2f(fmaf(s_acc[jn][3], LOG2E, -m2));
        sj[jn] = (p0 + p1) + (p2 + p3);
        fp16x2 lo = __builtin_amdgcn_cvt_pkrtz(p0, p1);
        fp16x2 hi = __builtin_amdgcn_cvt_pkrtz(p2, p3);
        pb[jn][0] = (_Float16)lo[0]; pb[jn][1] = (_Float16)lo[1];
        pb[jn][2] = (_Float16)hi[0]; pb[jn][3] = (_Float16)hi[1];
    }
    float sum = (sj[0] + sj[1]) + (sj[2] + sj[3]);
    sum += __shfl_xor(sum, 16);
    sum += __shfl_xor(sum, 32);
    l_i += sum;

#pragma unroll
    for (int im = 0; im < 4; im++)
#pragma unroll
        for (int ks = 0; ks < 4; ks++)
            o_acc[im] = __builtin_amdgcn_mfma_f32_16x16x16f16(*vfp[BUF][im][ks], pb[ks],
                                                              o_acc[im], 0, 0, 0);
}

__global__ __launch_bounds__(256) void attn_kernel(const _Float16* Q,
                                                   const _Float16* __restrict__ K,
                                                   const _Float16* __restrict__ Vt,
                                                   _Float16* O, int ld,
                                                   const float* __restrict__ woW,
                                                   _Float16* __restrict__ woT) {
    __shared__ _Float16 KVs[2][2][64 * 64];   // [buf][0=K,1=V] 32KB; Q pre-staged in KVs[1][0]
    if (blockIdx.z == 0) {
        // wo transpose-convert rides along (256 of 1024 z=0 blocks); aliases KVs as scratch.
        if (blockIdx.x < 16 && blockIdx.y < 16)
            convt_core((float(*)[65])&KVs[0][0][0], woW, 1024, woT, 1024, 1.f,
                       blockIdx.x * 64, blockIdx.y * 64);
        return;
    }
    int qt = blockIdx.x, bh = blockIdx.y;
    int b = bh >> 4, h = bh & 15;
    int col0 = h * 64, tbase = b * 2048;
    int tid = threadIdx.x;
    int wave = tid >> 6, lane = tid & 63, quad = lane >> 4, l15 = lane & 15;
    int lrow = lane >> 3, lch = lane & 7;

    const _Float16* kg[2];
    const _Float16* vg[2];
    const size_t kadv = (size_t)64 * ld;
#pragma unroll
    for (int i = 0; i < 2; i++) {
        int g = 2 * wave + i;
        int row = g * 8 + lrow;
        int ch = lch ^ (row & 7);
        kg[i] = K + (size_t)(tbase + row) * ld + col0 + ch * 8;
        vg[i] = Vt + ((size_t)bh * 64 + row) * 2048 + ch * 8;
        async16(Q + (size_t)(tbase + qt * 64 + row) * ld + col0 + ch * 8, &KVs[1][0][g * 512]);
        async16(kg[i], &KVs[0][0][g * 512]);
        async16(vg[i], &KVs[0][1][g * 512]);
        kg[i] += kadv;
        vg[i] += 64;
    }
    __syncthreads();   // drains Q + buf0

    // hoist Q fragments from KVs[1][0]; wave-local rows, lgkm wait before loop prefetch lands.
    int rowq = 16 * wave + l15;
    half8 bq[2];
#pragma unroll
    for (int kk = 0; kk < 2; kk++)
        bq[kk] = *(const half8*)&KVs[1][0][rowq * 64 + ((((kk << 2) | quad) ^ (rowq & 7)) << 3)];
    asm volatile("s_waitcnt lgkmcnt(0)" ::: "memory");
    __builtin_amdgcn_sched_barrier(0);

    const half8* kfp[2][4][2];
    const half4* vfp[2][4][4];
#pragma unroll
    for (int bb = 0; bb < 2; bb++) {
#pragma unroll
        for (int jn = 0; jn < 4; jn++) {
            int rowk = 16 * jn + l15;
#pragma unroll
            for (int kk = 0; kk < 2; kk++)
                kfp[bb][jn][kk] = (const half8*)
                    &KVs[bb][0][rowk * 64 + ((((kk << 2) | quad) ^ (rowk & 7)) << 3)];
        }
#pragma unroll
        for (int im = 0; im < 4; im++) {
            int rowv = 16 * im + l15;
#pragma unroll
            for (int ks = 0; ks < 4; ks++) {
                int off = rowv * 128 + ((((2 * ks) | (quad >> 1)) ^ (rowv & 7)) << 4)
                          + (quad & 1) * 8;
                vfp[bb][im][ks] = (const half4*)((const char*)KVs[bb][1] + off);
            }
        }
    }

    floatx4 o_acc[4];
#pragma unroll
    for (int im = 0; im < 4; im++)
#pragma unroll
        for (int r = 0; r < 4; r++) o_acc[im][r] = 0.f;
    float m_i = -1e30f, l_i = 0.f;

#pragma unroll 1
    for (int kt2 = 0; kt2 < 16; kt2++) {
        if (kt2) __syncthreads();
#pragma unroll
        for (int i = 0; i < 2; i++) {
            async16(kg[i], &KVs[1][0][(2 * wave + i) * 512]);
            async16(vg[i], &KVs[1][1][(2 * wave + i) * 512]);
            kg[i] += kadv;
            vg[i] += 64;
        }
        attn_step<0>(kfp, vfp, bq, o_acc, m_i, l_i);

        __syncthreads();
        if (kt2 < 15) {
#pragma unroll
            for (int i = 0; i < 2; i++) {
                async16(kg[i], &KVs[0][0][(2 * wave + i) * 512]);
                async16(vg[i], &KVs[0][1][(2 * wave + i) * 512]);
                kg[i] += kadv;
                vg[i] += 64;
            }
        }
        attn_step<1>(kfp, vfp, bq, o_acc, m_i, l_i);
    }

    float rl = 1.f / l_i;
#pragma unroll
    for (int im = 0; im < 4; im++) {
        half4 o;
#pragma unroll
        for (int r = 0; r < 4; r++) o[r] = (_Float16)(o_acc[im][r] * rl);
        *(half4*)&O[(size_t)(tbase + qt * 64 + wave * 16 + l15) * ld + col0 + im * 16 + quad * 4] = o;
    }
}

extern "C" void kernel_launch(void* const* d_in, const int* in_sizes, int n_in,
                              void* d_out, int out_size, void* d_ws, size_t ws_size,
                              hipStream_t stream) {
    const float* x   = (const float*)d_in[0];
    const float* wq  = (const float*)d_in[1];
    const float* wk  = (const float*)d_in[2];
    const float* wv  = (const float*)d_in[3];
    const float* wo  = (const float*)d_in[4];
    const float* w1  = (const float*)d_in[5];
    const float* b1  = (const float*)d_in[6];
    const float* w2  = (const float*)d_in[7];
    const float* b2  = (const float*)d_in[8];
    const float* g1  = (const float*)d_in[9];
    const float* be1 = (const float*)d_in[10];
    const float* g2  = (const float*)d_in[11];
    const float* be2 = (const float*)d_in[12];

    const size_t M1 = (size_t)1 << 20;
    _Float16* R0  = (_Float16*)d_ws;       // h -> woT -> h(LN2)
    _Float16* QKV = R0 + 4 * M1;           // [4096][3072] spans R0+4M1..R0+16M1 (V slice unused)
    _Float16* R3  = R0 + 12 * M1;          // valid scratch only after wo-gemm

    _Float16* wqkvT = (_Float16*)d_out;    // [3072][1024] fp16, bytes [0,6MB)
    _Float16* VtD = wqkvT + 3 * M1;        // Vt [32][64][2048] fp16, bytes [6MB,14MB)
    float* x1 = (float*)d_out;
    float* out = (float*)d_out;

    dim3 blk(256);

    // ln1 + wq/wk/wv convt fused (1/sqrt(64) folded into wq)
    pre_kernel<<<4864, blk, 0, stream>>>(x, g1, be1, R0, wq, wk, wv, wqkvT);
    // fused QKV GEMM (128x128, 768 blk = 3/CU, XCD-swizzled): Q,K -> QKV; V -> VtD transposed
    gemm_t128<<<dim3(24, 32), blk, 0, stream>>>(R0, 1024, wqkvT, QKV, VtD, 3072, 1024);
    // attention (z=1) + wo convt into R0 (z=0; R0 dead during attn)
    _Float16* woT = R0;
    attn_kernel<<<dim3(32, 32, 2), blk, 0, stream>>>(QKV, QKV + 1024, VtD, QKV, 3072, wo, woT);
    // x1 = attnout @ wo + x -> d_out
    gemm_t<<<dim3(8, 64), blk, 0, stream>>>(QKV, 3072, woT, nullptr, x, x1, 1024, 1024, 0, 0);
    // ln2 + FFN half-0 convts fused (R3 scratch valid: wo-gemm done)
    _Float16* w1Th = R3;
    _Float16* w2Th = R3 + 2 * M1;
    post_kernel<<<6144, blk, 0, stream>>>(x1, g2, be2, R0, w1, w1Th, w2, w2Th);
    // FFN half 0
    _Float16* f = QKV;
    gemm_t<<<dim3(16, 64), blk, 0, stream>>>(R0, 1024, w1Th, b1, nullptr, f, 2048, 1024, 1, 1);
    gemm_t<<<dim3(8, 64), blk, 0, stream>>>(f, 2048, w2Th, nullptr, x1, out, 1024, 2048, 0, 0);
    // FFN half 1
    convt_pair_kernel<<<dim3(32, 32, 2), blk, 0, stream>>>(
        w1 + 2048, 4096, w1Th, 1024, 32, 16,
        w2 + (size_t)2048 * 1024, 1024, w2Th, 2048, 16, 32);
    gemm_t<<<dim3(16, 64), blk, 0, stream>>>(R0, 1024, w1Th, b1 + 2048, nullptr, f, 2048, 1024, 1, 1);
    gemm_t<<<dim3(8, 64), blk, 0, stream>>>(f, 2048, w2Th, b2, x1, out, 1024, 2048, 0, 0);
}

// Round 15
// 415.425 us; speedup vs baseline: 1.0317x; 1.0006x over previous
//
#include <hip/hip_runtime.h>

// EncoderBlock: x:[2,2048,1024] FP32 in/out. Internal fp16 MFMA.
// B=2 S=2048 D=1024 H=16 DH=64 FF=4096, T=4096 tokens.
// ws (32MB): R0 8MB: h -> woT -> h(LN2)
//            R1..R3 24MB: fused QKV [4096][3072] (V slice unused) -> attn-out in Q slice
//                         -> f(R1+R2) + wscratch(R3 only after wo-gemm)
// d_out (16MB): wqkvT fp16 [0,6MB) + Vt fp16 [6MB,14MB) -> x1 fp32 -> final output.
// GEMM map (hard-won ledger):
//   QKV  -> gemm_t128 + Vt epilogue + XCD swizzle (768 blk = 3/CU)  [r5,r8,r14]
//   FFN1/wo/FFN2 -> gemm_t 64x128 + XCD swizzle [r15]
//     (128^2 LOST r2,r6; 2-phase db LOST r7; 32x128 LOST r13)
// attn ledger: QBLK=64 2-buffer 32KB, FROZEN core (r6/r8).
//   LOST: QBLK=128 (r9), bit_cast pb (r7), 3-buf vmcnt ring (r10), setprio (r11).
//   WON:  Q-in-KVs-buf staging (r6), max3 + defer-max (r5,r6), wo-convt rides z=0 (r12),
//         deferred l_i reduction (r15: per-lane partials, one reduce at end — alpha is
//         l15-uniform so partials stay exact).
// launches 13->10 (r12): pre_kernel (ln1+qkv convt), post_kernel (ln2+ffn0 convt).

typedef _Float16 half8 __attribute__((ext_vector_type(8)));
typedef _Float16 half4 __attribute__((ext_vector_type(4)));
typedef __fp16 fp16x2 __attribute__((ext_vector_type(2)));
typedef float floatx4 __attribute__((ext_vector_type(4)));

#define MAX3(a, b, c) fmaxf(fmaxf((a), (b)), (c))

__device__ __forceinline__ void async16(const void* g, void* l) {
    __builtin_amdgcn_global_load_lds((const __attribute__((address_space(1))) unsigned int*)g,
                                     (__attribute__((address_space(3))) unsigned int*)l,
                                     16, 0, 0);
}

// ---------------- LayerNorm body fp32 -> fp16 (ddof=1, g*(x-mean)/(std+eps)+b) ----
__device__ __forceinline__ void ln_body(const float* __restrict__ x,
                                        const float* __restrict__ g,
                                        const float* __restrict__ be,
                                        _Float16* __restrict__ out, int row) {
    int tid = threadIdx.x;
    floatx4 v = ((const floatx4*)(x + (size_t)row * 1024))[tid];
    float s = 0.f, ss = 0.f;
#pragma unroll
    for (int i = 0; i < 4; i++) { s += v[i]; ss += v[i] * v[i]; }
#pragma unroll
    for (int off = 1; off < 64; off <<= 1) {
        s += __shfl_xor(s, off);
        ss += __shfl_xor(ss, off);
    }
    __shared__ float sm[8];
    int wave = tid >> 6, lane = tid & 63;
    if (lane == 0) { sm[wave] = s; sm[wave + 4] = ss; }
    __syncthreads();
    s = sm[0] + sm[1] + sm[2] + sm[3];
    ss = sm[4] + sm[5] + sm[6] + sm[7];
    float mean = s * (1.f / 1024.f);
    float var = (ss - s * mean) * (1.f / 1023.f);
    float rs = 1.f / (sqrtf(fmaxf(var, 0.f)) + 1e-6f);
    floatx4 gv = ((const floatx4*)g)[tid];
    floatx4 bv = ((const floatx4*)be)[tid];
    half4 o;
#pragma unroll
    for (int i = 0; i < 4; i++) o[i] = (_Float16)(gv[i] * (v[i] - mean) * rs + bv[i]);
    ((half4*)(out + (size_t)row * 1024))[tid] = o;
}

// ------- Transpose-convert core: W[Kr][Nr] fp32 (row stride ldW) -> WT[Nr][Kr] fp16 * scale --
__device__ __forceinline__ void convt_core(float (*t)[65], const float* __restrict__ W, int ldW,
                                           _Float16* __restrict__ WT, int Kr, float scale,
                                           int n0, int k0) {
    int tid = threadIdx.x;
    int r = tid >> 4, c4 = (tid & 15) * 4;
#pragma unroll
    for (int p = 0; p < 4; p++) {
        floatx4 v = *(const floatx4*)(W + (size_t)(k0 + r + p * 16) * ldW + n0 + c4);
#pragma unroll
        for (int j = 0; j < 4; j++) t[c4 + j][r + p * 16] = v[j];
    }
    __syncthreads();
#pragma unroll
    for (int p = 0; p < 4; p++) {
        int rr = r + p * 16;
        half4 o;
#pragma unroll
        for (int j = 0; j < 4; j++) o[j] = (_Float16)(t[rr][c4 + j] * scale);
        *(half4*)(WT + (size_t)(n0 + rr) * Kr + k0 + c4) = o;
    }
}

__device__ __forceinline__ void convt_body(const float* __restrict__ W, int ldW,
                                           _Float16* __restrict__ WT, int Kr, float scale,
                                           int n0, int k0) {
    __shared__ float t[64][65];
    convt_core(t, W, ldW, WT, Kr, scale, n0, k0);
}

// ---- pre_kernel: ln1 (blocks 0..4095) + wq/wk/wv convt (blocks 4096..4863) ----
__global__ __launch_bounds__(256) void pre_kernel(const float* __restrict__ x,
                                                  const float* __restrict__ g1,
                                                  const float* __restrict__ be1,
                                                  _Float16* __restrict__ h,
                                                  const float* __restrict__ wq,
                                                  const float* __restrict__ wk,
                                                  const float* __restrict__ wv,
                                                  _Float16* __restrict__ QT) {
    int bid = blockIdx.x;
    if (bid < 4096) { ln_body(x, g1, be1, h, bid); return; }
    int rem = bid - 4096;
    int z = rem >> 8, xy = rem & 255;
    const float* W = (z == 0) ? wq : (z == 1) ? wk : wv;
    convt_body(W, 1024, QT + (size_t)z * 1024 * 1024, 1024, (z == 0) ? 0.125f : 1.f,
               (xy & 15) * 64, (xy >> 4) * 64);
}

// ---- post_kernel: ln2 (blocks 0..4095) + FFN half-0 convts (blocks 4096..6143) ----
__global__ __launch_bounds__(256) void post_kernel(const float* __restrict__ x1,
                                                   const float* __restrict__ g2,
                                                   const float* __restrict__ be2,
                                                   _Float16* __restrict__ h,
                                                   const float* __restrict__ w1h,
                                                   _Float16* __restrict__ w1T,
                                                   const float* __restrict__ w2h,
                                                   _Float16* __restrict__ w2T) {
    int bid = blockIdx.x;
    if (bid < 4096) { ln_body(x1, g2, be2, h, bid); return; }
    int rem = bid - 4096;            // 0..2047
    int z = rem >> 10, xy = rem & 1023;
    int xx = xy & 31, yy = xy >> 5;
    if (z == 0) {
        if (yy < 16) convt_body(w1h, 4096, w1T, 1024, 1.f, xx * 64, yy * 64);   // 32x16
    } else {
        if (xx < 16) convt_body(w2h, 1024, w2T, 2048, 1.f, xx * 64, yy * 64);   // 16x32
    }
}

// two convt jobs in one launch (z selects); blocks outside the job's grid exit. (FFN half-1)
__global__ __launch_bounds__(256) void convt_pair_kernel(const float* __restrict__ Wa, int ldWa,
                                                         _Float16* __restrict__ WTa, int Kra,
                                                         int gxa, int gya,
                                                         const float* __restrict__ Wb, int ldWb,
                                                         _Float16* __restrict__ WTb, int Krb,
                                                         int gxb, int gyb) {
    int z = blockIdx.z;
    const float* W = z ? Wb : Wa;
    _Float16* WT = z ? WTb : WTa;
    int ldW = z ? ldWb : ldWa;
    int Kr = z ? Krb : Kra;
    int gx = z ? gxb : gxa, gy = z ? gyb : gya;
    if ((int)blockIdx.x >= gx || (int)blockIdx.y >= gy) return;
    convt_body(W, ldW, WT, Kr, 1.f, blockIdx.x * 64, blockIdx.y * 64);
}

// ------- MFMA GEMM 64x128: C = [relu](A@BT^T + bias) + res --------
// A [M][lda] fp16, BT [N][K] fp16. 4 waves x (32x64), BK=64. FFN1/wo/FFN2.
// T1 XCD swizzle (grid always %8==0): each XCD owns gridDim.x/8 consecutive
// bn-columns x all bm -> B-panel XCD-local L2-resident.
__global__ __launch_bounds__(256) void gemm_t(const _Float16* __restrict__ A, int lda,
                                              const _Float16* __restrict__ BT,
                                              const float* __restrict__ bias,
                                              const float* res, void* Cout,
                                              int N, int K, int relu_flag, int out_fp16) {
    __shared__ _Float16 As[64 * 64];    // 8KB
    __shared__ _Float16 Bs[128 * 64];   // 16KB
    int tid = threadIdx.x;
    int wave = tid >> 6, lane = tid & 63, quad = lane >> 4, l15 = lane & 15;
    int lin = blockIdx.y * gridDim.x + blockIdx.x;
    int chunk = (gridDim.x * gridDim.y) >> 3;
    int swz = (lin & 7) * chunk + (lin >> 3);
    int bxx = swz / (int)gridDim.y;
    int byy = swz - bxx * (int)gridDim.y;
    int bm = byy * 64, bn = bxx * 128;
    int wr = (wave & 1) * 32, wc = (wave >> 1) * 64;
    int lrow = lane >> 3, lch = lane & 7;

    floatx4 acc[2][4];
#pragma unroll
    for (int im = 0; im < 2; im++)
#pragma unroll
        for (int in = 0; in < 4; in++)
#pragma unroll
            for (int r = 0; r < 4; r++) acc[im][in][r] = 0.f;

    for (int k0 = 0; k0 < K; k0 += 64) {
        __syncthreads();
#pragma unroll
        for (int ia = 0; ia < 2; ia++) {
            int g = 2 * wave + ia;
            int row = g * 8 + lrow;
            int ch = lch ^ (row & 7);
            async16(A + (size_t)(bm + row) * lda + k0 + ch * 8, &As[g * 512]);
        }
#pragma unroll
        for (int ib = 0; ib < 4; ib++) {
            int g = 4 * wave + ib;
            int row = g * 8 + lrow;
            int ch = lch ^ (row & 7);
            async16(BT + (size_t)(bn + row) * K + k0 + ch * 8, &Bs[g * 512]);
        }
        __syncthreads();

        half8 af[2][2], bf[4][2];
#pragma unroll
        for (int kk = 0; kk < 2; kk++) {
#pragma unroll
            for (int im = 0; im < 2; im++) {
                int m = wr + im * 16 + l15;
                af[im][kk] = *(const half8*)&As[m * 64 + ((((kk << 2) | quad) ^ (m & 7)) << 3)];
            }
#pragma unroll
            for (int in = 0; in < 4; in++) {
                int n = wc + in * 16 + l15;
                bf[in][kk] = *(const half8*)&Bs[n * 64 + ((((kk << 2) | quad) ^ (n & 7)) << 3)];
            }
        }
#pragma unroll
        for (int kk = 0; kk < 2; kk++)
#pragma unroll
            for (int im = 0; im < 2; im++)
#pragma unroll
                for (int in = 0; in < 4; in++)
                    acc[im][in] = __builtin_amdgcn_mfma_f32_16x16x32_f16(af[im][kk], bf[in][kk],
                                                                         acc[im][in], 0, 0, 0);
    }
#pragma unroll
    for (int im = 0; im < 2; im++)
#pragma unroll
        for (int in = 0; in < 4; in++)
#pragma unroll
            for (int r = 0; r < 4; r++) {
                int row = bm + wr + im * 16 + quad * 4 + r;
                int col = bn + wc + in * 16 + l15;
                float val = acc[im][in][r];
                if (bias) val += bias[col];
                if (relu_flag) val = fmaxf(val, 0.f);
                if (res) val += res[(size_t)row * N + col];
                if (out_fp16) ((_Float16*)Cout)[(size_t)row * N + col] = (_Float16)val;
                else          ((float*)Cout)[(size_t)row * N + col] = val;
            }
}

// ------- MFMA GEMM 128x128 (m97 structure): 4 waves x (64x64, 4x4 acc), BK=64, 32KB LDS.
// QKV only (grid FIXED 24x32 = 768 blk = 3/CU). XCD swizzle: each XCD owns 3
// consecutive bn-columns x all bm. Blocks with bn>=2048 (V slice) write output
// TRANSPOSED into Vt[bh=32][dh=64][s=2048] (kills transv kernel).
__global__ __launch_bounds__(256) void gemm_t128(const _Float16* __restrict__ A, int lda,
                                                 const _Float16* __restrict__ BT,
                                                 _Float16* __restrict__ Cout,
                                                 _Float16* __restrict__ VtOut,
                                                 int N, int K) {
    __shared__ _Float16 As[128 * 64];   // 16KB
    __shared__ _Float16 Bs[128 * 64];   // 16KB
    int tid = threadIdx.x;
    int wave = tid >> 6, lane = tid & 63, quad = lane >> 4, l15 = lane & 15;
    int lin = blockIdx.y * 24 + blockIdx.x;
    int swz = (lin & 7) * 96 + (lin >> 3);
    int bxx = swz / 32;        // 0..23; each XCD covers 3 consecutive bxx
    int byy = swz - bxx * 32;  // 0..31
    int bm = byy * 128, bn = bxx * 128;
    int wr = (wave & 1) * 64, wc = (wave >> 1) * 64;
    int lrow = lane >> 3, lch = lane & 7;

    floatx4 acc[4][4];
#pragma unroll
    for (int im = 0; im < 4; im++)
#pragma unroll
        for (int in = 0; in < 4; in++)
#pragma unroll
            for (int r = 0; r < 4; r++) acc[im][in][r] = 0.f;

    for (int k0 = 0; k0 < K; k0 += 64) {
        __syncthreads();
#pragma unroll
        for (int ia = 0; ia < 4; ia++) {
            int g = 4 * wave + ia;
            int row = g * 8 + lrow;
            int ch = lch ^ (row & 7);
            async16(A + (size_t)(bm + row) * lda + k0 + ch * 8, &As[g * 512]);
        }
#pragma unroll
        for (int ib = 0; ib < 4; ib++) {
            int g = 4 * wave + ib;
            int row = g * 8 + lrow;
            int ch = lch ^ (row & 7);
            async16(BT + (size_t)(bn + row) * K + k0 + ch * 8, &Bs[g * 512]);
        }
        __syncthreads();

        half8 af[4][2], bf[4][2];
#pragma unroll
        for (int kk = 0; kk < 2; kk++) {
#pragma unroll
            for (int im = 0; im < 4; im++) {
                int m = wr + im * 16 + l15;
                af[im][kk] = *(const half8*)&As[m * 64 + ((((kk << 2) | quad) ^ (m & 7)) << 3)];
            }
#pragma unroll
            for (int in = 0; in < 4; in++) {
                int n = wc + in * 16 + l15;
                bf[in][kk] = *(const half8*)&Bs[n * 64 + ((((kk << 2) | quad) ^ (n & 7)) << 3)];
            }
        }
#pragma unroll
        for (int kk = 0; kk < 2; kk++)
#pragma unroll
            for (int im = 0; im < 4; im++)
#pragma unroll
                for (int in = 0; in < 4; in++)
                    acc[im][in] = __builtin_amdgcn_mfma_f32_16x16x32_f16(af[im][kk], bf[in][kk],
                                                                         acc[im][in], 0, 0, 0);
    }
    if (VtOut && bn >= 2048) {
#pragma unroll
        for (int im = 0; im < 4; im++) {
            int rowbase = bm + wr + im * 16 + quad * 4;
            int b = rowbase >> 11, s = rowbase & 2047;
#pragma unroll
            for (int in = 0; in < 4; in++) {
                int vcol = bn - 2048 + wc + in * 16 + l15;
                int bh = b * 16 + (vcol >> 6);
                int dh = vcol & 63;
                half4 o;
#pragma unroll
                for (int r = 0; r < 4; r++) o[r] = (_Float16)acc[im][in][r];
                *(half4*)&VtOut[((size_t)bh * 64 + dh) * 2048 + s] = o;
            }
        }
    } else {
#pragma unroll
        for (int im = 0; im < 4; im++)
#pragma unroll
            for (int in = 0; in < 4; in++)
#pragma unroll
                for (int r = 0; r < 4; r++) {
                    int row = bm + wr + im * 16 + quad * 4 + r;
                    int col = bn + wc + in * 16 + l15;
                    Cout[(size_t)row * N + col] = (_Float16)acc[im][in][r];
                }
    }
}

// ---------------- Flash attention v3 (r6/r8 proven config, FROZEN core) ----------
// S^T trick + double-buffered K/V. Q pre-scaled via wq. One barrier per kt.
// Q staged into KVs[1][0] (dead after bq hoist) -> 32KB LDS.
// l_i kept as PER-LANE partial (alpha is l15-uniform); one cross-lane reduce at end.
// z=0 blocks instead run the wo transpose-convert (aliasing this kernel's LDS).
template <int BUF>
__device__ __forceinline__ void attn_step(const half8* const (&kfp)[2][4][2],
                                          const half4* const (&vfp)[2][4][4],
                                          const half8 (&bq)[2],
                                          floatx4 (&o_acc)[4],
                                          float& m_i, float& l_i) {
    const float LOG2E = 1.44269504f;
    floatx4 s_acc[4];
#pragma unroll
    for (int jn = 0; jn < 4; jn++)
#pragma unroll
        for (int r = 0; r < 4; r++) s_acc[jn][r] = 0.f;
#pragma unroll
    for (int jn = 0; jn < 4; jn++)
#pragma unroll
        for (int kk = 0; kk < 2; kk++)
            s_acc[jn] = __builtin_amdgcn_mfma_f32_16x16x32_f16(*kfp[BUF][jn][kk], bq[kk],
                                                               s_acc[jn], 0, 0, 0);

    // online softmax with deferred max (THR=8); max3 tree
    float t0 = MAX3(s_acc[0][0], s_acc[0][1], s_acc[0][2]);
    float t1 = MAX3(s_acc[0][3], s_acc[1][0], s_acc[1][1]);
    float t2 = MAX3(s_acc[1][2], s_acc[1][3], s_acc[2][0]);
    float t3 = MAX3(s_acc[2][1], s_acc[2][2], s_acc[2][3]);
    float t4 = MAX3(s_acc[3][0], s_acc[3][1], s_acc[3][2]);
    float mx = MAX3(MAX3(t0, t1, t2), fmaxf(t3, t4), s_acc[3][3]);
    mx = fmaxf(mx, __shfl_xor(mx, 16));
    mx = fmaxf(mx, __shfl_xor(mx, 32));
    if (!__all(mx <= m_i + 8.f)) {
        float mnew = fmaxf(m_i, mx);
        float dd = m_i - mnew;
        float alpha = (dd < -60.f) ? 0.f : __expf(dd);
        l_i *= alpha;           // per-lane partial; alpha uniform across l15 group
#pragma unroll
        for (int im = 0; im < 4; im++)
#pragma unroll
            for (int r = 0; r < 4; r++) o_acc[im][r] *= alpha;
        m_i = mnew;
    }
    float m2 = m_i * LOG2E;

    float sj[4];
    half4 pb[4];   // P^T C-layout regs ARE B-fragments of mfma_16x16x16 (k=quad*4+j)
#pragma unroll
    for (int jn = 0; jn < 4; jn++) {
        float p0 = exp2f(fmaf(s_acc[jn][0], LOG2E, -m2));
        float p1 = exp2f(fmaf(s_acc[jn][1], LOG2E, -m2));
        float p2 = exp2f(fmaf(s_acc[jn][2], LOG2E, -m2));
        float p3 = exp2f(fmaf(s_acc[jn][3], LOG2E, -m2));
        sj[jn] = (p0 + p1) + (p2 + p3);
        fp16x2 lo = __builtin_amdgcn_cvt_pkrtz(p0, p1);
        fp16x2 hi = __builtin_amdgcn_cvt_pkrtz(p2, p3);
        pb[jn][0] = (_Float16)lo[0]; pb[jn][1] = (_Float16)lo[1];
        pb[jn][2] = (_Float16)hi[0]; pb[jn][3] = (_Float16)hi[1];
    }
    l_i += (sj[0] + sj[1]) + (sj[2] + sj[3]);   // no per-step cross-lane reduce

#pragma unroll
    for (int im = 0; im < 4; im++)
#pragma unroll
        for (int ks = 0; ks < 4; ks++)
            o_acc[im] = __builtin_amdgcn_mfma_f32_16x16x16f16(*vfp[BUF][im][ks], pb[ks],
                                                              o_acc[im], 0, 0, 0);
}

__global__ __launch_bounds__(256) void attn_kernel(const _Float16* Q,
                                                   const _Float16* __restrict__ K,
                                                   const _Float16* __restrict__ Vt,
                                                   _Float16* O, int ld,
                                                   const float* __restrict__ woW,
                                                   _Float16* __restrict__ woT) {
    __shared__ _Float16 KVs[2][2][64 * 64];   // [buf][0=K,1=V] 32KB; Q pre-staged in KVs[1][0]
    if (blockIdx.z == 0) {
        // wo transpose-convert rides along (256 of 1024 z=0 blocks); aliases KVs as scratch.
        if (blockIdx.x < 16 && blockIdx.y < 16)
            convt_core((float(*)[65])&KVs[0][0][0], woW, 1024, woT, 1024, 1.f,
                       blockIdx.x * 64, blockIdx.y * 64);
        return;
    }
    int qt = blockIdx.x, bh = blockIdx.y;
    int b = bh >> 4, h = bh & 15;
    int col0 = h * 64, tbase = b * 2048;
    int tid = threadIdx.x;
    int wave = tid >> 6, lane = tid & 63, quad = lane >> 4, l15 = lane & 15;
    int lrow = lane >> 3, lch = lane & 7;

    const _Float16* kg[2];
    const _Float16* vg[2];
    const size_t kadv = (size_t)64 * ld;
#pragma unroll
    for (int i = 0; i < 2; i++) {
        int g = 2 * wave + i;
        int row = g * 8 + lrow;
        int ch = lch ^ (row & 7);
        kg[i] = K + (size_t)(tbase + row) * ld + col0 + ch * 8;
        vg[i] = Vt + ((size_t)bh * 64 + row) * 2048 + ch * 8;
        async16(Q + (size_t)(tbase + qt * 64 + row) * ld + col0 + ch * 8, &KVs[1][0][g * 512]);
        async16(kg[i], &KVs[0][0][g * 512]);
        async16(vg[i], &KVs[0][1][g * 512]);
        kg[i] += kadv;
        vg[i] += 64;
    }
    __syncthreads();   // drains Q + buf0

    // hoist Q fragments from KVs[1][0]; wave-local rows, lgkm wait before loop prefetch lands.
    int rowq = 16 * wave + l15;
    half8 bq[2];
#pragma unroll
    for (int kk = 0; kk < 2; kk++)
        bq[kk] = *(const half8*)&KVs[1][0][rowq * 64 + ((((kk << 2) | quad) ^ (rowq & 7)) << 3)];
    asm volatile("s_waitcnt lgkmcnt(0)" ::: "memory");
    __builtin_amdgcn_sched_barrier(0);

    const half8* kfp[2][4][2];
    const half4* vfp[2][4][4];
#pragma unroll
    for (int bb = 0; bb < 2; bb++) {
#pragma unroll
        for (int jn = 0; jn < 4; jn++) {
            int rowk = 16 * jn + l15;
#pragma unroll
            for (int kk = 0; kk < 2; kk++)
                kfp[bb][jn][kk] = (const half8*)
                    &KVs[bb][0][rowk * 64 + ((((kk << 2) | quad) ^ (rowk & 7)) << 3)];
        }
#pragma unroll
        for (int im = 0; im < 4; im++) {
            int rowv = 16 * im + l15;
#pragma unroll
            for (int ks = 0; ks < 4; ks++) {
                int off = rowv * 128 + ((((2 * ks) | (quad >> 1)) ^ (rowv & 7)) << 4)
                          + (quad & 1) * 8;
                vfp[bb][im][ks] = (const half4*)((const char*)KVs[bb][1] + off);
            }
        }
    }

    floatx4 o_acc[4];
#pragma unroll
    for (int im = 0; im < 4; im++)
#pragma unroll
        for (int r = 0; r < 4; r++) o_acc[im][r] = 0.f;
    float m_i = -1e30f, l_i = 0.f;

#pragma unroll 1
    for (int kt2 = 0; kt2 < 16; kt2++) {
        if (kt2) __syncthreads();
#pragma unroll
        for (int i = 0; i < 2; i++) {
            async16(kg[i], &KVs[1][0][(2 * wave + i) * 512]);
            async16(vg[i], &KVs[1][1][(2 * wave + i) * 512]);
            kg[i] += kadv;
            vg[i] += 64;
        }
        attn_step<0>(kfp, vfp, bq, o_acc, m_i, l_i);

        __syncthreads();
        if (kt2 < 15) {
#pragma unroll
            for (int i = 0; i < 2; i++) {
                async16(kg[i], &KVs[0][0][(2 * wave + i) * 512]);
                async16(vg[i], &KVs[0][1][(2 * wave + i) * 512]);
                kg[i] += kadv;
                vg[i] += 64;
            }
        }
        attn_step<1>(kfp, vfp, bq, o_acc, m_i, l_i);
    }

    // final cross-lane l_i reduction (deferred from per-kt)
    l_i += __shfl_xor(l_i, 16);
    l_i += __shfl_xor(l_i, 32);
    float rl = 1.f / l_i;
#pragma unroll
    for (int im = 0; im < 4; im++) {
        half4 o;
#pragma unroll
        for (int r = 0; r < 4; r++) o[r] = (_Float16)(o_acc[im][r] * rl);
        *(half4*)&O[(size_t)(tbase + qt * 64 + wave * 16 + l15) * ld + col0 + im * 16 + quad * 4] = o;
    }
}

extern "C" void kernel_launch(void* const* d_in, const int* in_sizes, int n_in,
                              void* d_out, int out_size, void* d_ws, size_t ws_size,
                              hipStream_t stream) {
    const float* x   = (const float*)d_in[0];
    const float* wq  = (const float*)d_in[1];
    const float* wk  = (const float*)d_in[2];
    const float* wv  = (const float*)d_in[3];
    const float* wo  = (const float*)d_in[4];
    const float* w1  = (const float*)d_in[5];
    const float* b1  = (const float*)d_in[6];
    const float* w2  = (const float*)d_in[7];
    const float* b2  = (const float*)d_in[8];
    const float* g1  = (const float*)d_in[9];
    const float* be1 = (const float*)d_in[10];
    const float* g2  = (const float*)d_in[11];
    const float* be2 = (const float*)d_in[12];

    const size_t M1 = (size_t)1 << 20;
    _Float16* R0  = (_Float16*)d_ws;       // h -> woT -> h(LN2)
    _Float16* QKV = R0 + 4 * M1;           // [4096][3072] spans R0+4M1..R0+16M1 (V slice unused)
    _Float16* R3  = R0 + 12 * M1;          // valid scratch only after wo-gemm

    _Float16* wqkvT = (_Float16*)d_out;    // [3072][1024] fp16, bytes [0,6MB)
    _Float16* VtD = wqkvT + 3 * M1;        // Vt [32][64][2048] fp16, bytes [6MB,14MB)
    float* x1 = (float*)d_out;
    float* out = (float*)d_out;

    dim3 blk(256);

    // ln1 + wq/wk/wv convt fused (1/sqrt(64) folded into wq)
    pre_kernel<<<4864, blk, 0, stream>>>(x, g1, be1, R0, wq, wk, wv, wqkvT);
    // fused QKV GEMM (128x128, 768 blk = 3/CU, XCD-swizzled): Q,K -> QKV; V -> VtD transposed
    gemm_t128<<<dim3(24, 32), blk, 0, stream>>>(R0, 1024, wqkvT, QKV, VtD, 3072, 1024);
    // attention (z=1) + wo convt into R0 (z=0; R0 dead during attn)
    _Float16* woT = R0;
    attn_kernel<<<dim3(32, 32, 2), blk, 0, stream>>>(QKV, QKV + 1024, VtD, QKV, 3072, wo, woT);
    // x1 = attnout @ wo + x -> d_out
    gemm_t<<<dim3(8, 64), blk, 0, stream>>>(QKV, 3072, woT, nullptr, x, x1, 1024, 1024, 0, 0);
    // ln2 + FFN half-0 convts fused (R3 scratch valid: wo-gemm done)
    _Float16* w1Th = R3;
    _Float16* w2Th = R3 + 2 * M1;
    post_kernel<<<6144, blk, 0, stream>>>(x1, g2, be2, R0, w1, w1Th, w2, w2Th);
    // FFN half 0
    _Float16* f = QKV;
    gemm_t<<<dim3(16, 64), blk, 0, stream>>>(R0, 1024, w1Th, b1, nullptr, f, 2048, 1024, 1, 1);
    gemm_t<<<dim3(8, 64), blk, 0, stream>>>(f, 2048, w2Th, nullptr, x1, out, 1024, 2048, 0, 0);
    // FFN half 1
    convt_pair_kernel<<<dim3(32, 32, 2), blk, 0, stream>>>(
        w1 + 2048, 4096, w1Th, 1024, 32, 16,
        w2 + (size_t)2048 * 1024, 1024, w2Th, 2048, 16, 32);
    gemm_t<<<dim3(16, 64), blk, 0, stream>>>(R0, 1024, w1Th, b1 + 2048, nullptr, f, 2048, 1024, 1, 1);
    gemm_t<<<dim3(8, 64), blk, 0, stream>>>(f, 2048, w2Th, b2, x1, out, 1024, 2048, 0, 0);
}